// Round 2
// baseline (228.149 us; speedup 1.0000x reference)
//
#include <hip/hip_runtime.h>
#include <hip/hip_bf16.h>

// Problem constants
#define BATCH   4096
#define SDIM    512
#define ADIM    64
#define IDIM    577           // 512 + 64 + 1
#define KP2     576           // GEMM K = s+a exactly; r handled rank-1
#define NKT32   18            // K-tiles of 32
#define HDIM    2048
#define ZDIM    8192          // 4*HDIM
#define BUFE    (128 * 32)    // LDS elems per buffer (8KB)

typedef __attribute__((ext_vector_type(8))) __bf16 bf16x8;
typedef __attribute__((ext_vector_type(4))) float  accx4;

// ---------------------------------------------------------------------------
// Fused setup kernel (unchanged). Role by flat blockIdx:
//   [0,1152)     transpose Wx rows 0..575: 64k x 64n tiles -> wxt [8192][576]
//   [1152,1664)  zh partials (16 k-splits): zh_w[ky][n] = sum h*Wh
//   [1664,5760)  prep xb rows: bf16 [s|a] (4096 x 576)
//   [5760,5888)  transpose Wa [2048,64]f32 -> waT [64][2048]bf16
// ---------------------------------------------------------------------------
__global__ __launch_bounds__(256) void setup_kernel(
    const float* __restrict__ s, const float* __restrict__ a_prev,
    const float* __restrict__ h,
    const float* __restrict__ wx, const float* __restrict__ wh,
    const float* __restrict__ wa,
    __hip_bfloat16* __restrict__ xb, __hip_bfloat16* __restrict__ wxt,
    __hip_bfloat16* __restrict__ waT, float* __restrict__ zh_w)
{
    __shared__ float stile[64 * 65];        // 16.6KB, stride 65 (conflict-free)
    const int bid = blockIdx.x;
    const int t = threadIdx.x;

    if (bid < 1152) {                       // ---- transpose Wx (64k x 64n)
        const int kt2 = bid >> 7;           // 0..8
        const int nt  = bid & 127;          // 0..127
        const int c4  = t & 15;             // float4 column
        const int rr  = t >> 4;             // 0..15
#pragma unroll
        for (int i = 0; i < 4; ++i) {
            const int r = rr + i * 16;      // k within tile
            const int k = kt2 * 64 + r;
            float4 v =
                *(const float4*)(wx + (size_t)k * ZDIM + nt * 64 + c4 * 4);
            *(float4*)(stile + r * 65 + c4 * 4) = v;
        }
        __syncthreads();
        const int ch = t & 7;               // k-chunk
#pragma unroll
        for (int i = 0; i < 2; ++i) {
            const int nr = (t >> 3) + i * 32;   // n-row 0..63
            bf16x8 w8;
#pragma unroll
            for (int j = 0; j < 8; ++j)
                w8[j] = (__bf16)stile[(ch * 8 + j) * 65 + nr];
            *(bf16x8*)(wxt + (size_t)(nt * 64 + nr) * KP2 + kt2 * 64 + ch * 8)
                = w8;
        }
    } else if (bid < 1664) {                // ---- zh partials (16 k-splits)
        const int zb = bid - 1152;
        const int nb = zb & 31, ky = zb >> 5;       // nb 0..31, ky 0..15
        const int n  = nb * 256 + t;
        const float* hp  = h + ky * 128;
        const float* whp = wh + (size_t)ky * 128 * ZDIM + n;
        float p = 0.0f;
#pragma unroll 32
        for (int kk = 0; kk < 128; ++kk)
            p = fmaf(hp[kk], whp[(size_t)kk * ZDIM], p);
        zh_w[ky * ZDIM + n] = p;
    } else if (bid < 5760) {                // ---- prep xb row (s|a only)
        const int row = bid - 1664;
        const float* srow = s + (size_t)row * SDIM;
        const float* arow = a_prev + (size_t)row * ADIM;
        __hip_bfloat16* xrow = xb + (size_t)row * KP2;
        for (int c = t; c < KP2; c += 256) {
            const float v = (c < SDIM) ? srow[c] : arow[c - SDIM];
            xrow[c] = __float2bfloat16(v);
        }
    } else {                                // ---- transpose Wa (32k x 32a)
        const int wb = bid - 5760;
        const int kt = wb >> 1, at = wb & 1;
        const int c  = t & 31, r0 = t >> 5;
#pragma unroll
        for (int i = 0; i < 4; ++i) {
            int r = r0 + i * 8;             // k within tile
            stile[r * 33 + c] = wa[(size_t)(kt * 32 + r) * ADIM + at * 32 + c];
        }
        __syncthreads();
#pragma unroll
        for (int i = 0; i < 4; ++i) {
            int r = r0 + i * 8;             // action within tile
            waT[(size_t)(at * 32 + r) * HDIM + kt * 32 + c] =
                __float2bfloat16(stile[c * 33 + r]);
        }
    }
}

// ---------------------------------------------------------------------------
// Main bf16 MFMA GEMM + fused LSTM epilogue.
// R12 change (occupancy): BK 64 -> 32. LDS/block 64KB -> 32KB so 4-5 blocks
// fit per CU (was 2): 16-20 waves/CU vs 8. R1 showed NO pipe saturated
// (MFMA 28%, LDS ~50%, VALU 36%) -> latency-bound at 2 waves/SIMD; this
// adds TLP without changing FLOPs, LDS bytes, staging loads, or barrier
// count (1/tile x 18 == 2/tile x 9).
// Loop form (single barrier per tile, counted wait):
//   kt: vmcnt(0)       // waits ONLY stage(kt), issued one full compute ago
//       s_barrier      // publishes buf[kt&1]; also: all waves' compute(kt-1)
//                      //   ds_reads completed (lgkmcnt before their MFMAs,
//                      //   MFMAs precede this barrier) -> buf[(kt+1)&1]
//                      //   is safe to overwrite
//       stage(kt+1)    // 4 loads in flight across the whole compute
//       ds_read(8) + lgkmcnt(compiler) + 16 MFMA
// Swizzle (rows now 64B): read slot sl = ck ^ ((row>>1)&3); a wave's 64
// lanes cover all 64 16B-slots of its 1KB fragment region exactly once
// (conflict-free). Staging source chunk c = (lane&3)^((lane>>3)&3) is the
// matching involution (global_load_lds dest stays linear).
// ---------------------------------------------------------------------------
__device__ __forceinline__ float rcp_f(float x) {
    return __builtin_amdgcn_rcpf(x);
}
__device__ __forceinline__ float sigmoid_f(float x) {
    return rcp_f(1.0f + __expf(-x));          // stable: x->-inf => rcp(inf)=0
}
__device__ __forceinline__ float tanh_f(float x) {
    return 1.0f - 2.0f * rcp_f(1.0f + __expf(2.0f * x)); // stable both ends
}

__global__ __launch_bounds__(256, 4) void lstm_gemm(
    const __hip_bfloat16* __restrict__ xb,   // [4096][576] bf16
    const __hip_bfloat16* __restrict__ wxt,  // [8192][576] bf16 (n-major)
    const float* __restrict__ zh_w,          // [16][8192] k-split partials
    const float* __restrict__ bh,            // [8192]
    const float* __restrict__ cvec,          // [2048]
    const float* __restrict__ wx,            // [577][8192] f32 (row 576 used)
    const float* __restrict__ r_prev,        // [4096]
    __hip_bfloat16* __restrict__ hout)       // [4096][2048] bf16
{
    __shared__ __bf16 smA[2 * BUFE];   // 16KB  [buf][row][slot swizzled]
    __shared__ __bf16 smB[2 * BUFE];   // 16KB  [buf][zcol][slot swizzled]
    const int t    = threadIdx.x;
    const int lane = t & 63;
    const int wid  = t >> 6;
    const int m0   = blockIdx.x * 128;
    const int n0   = blockIdx.y * 32;
    const int wm   = wid >> 1, wn = wid & 1;
    const int fl15 = lane & 15;
    const int fhi  = lane >> 4;        // 0..3

    accx4 acc[4][4] = {};              // [gate][rowtile]

    // ---- staging addresses (loop-invariant) ----
    const int lrow = lane >> 2;        // 0..15 (row within 1KB wave-load)
    const int lsl  = lane & 3;         // linear LDS slot
    const int cch  = lsl ^ ((lane >> 3) & 3);   // content chunk (involution)
    const __bf16* gA[2]; const __bf16* gB[2]; int lofs[2];
#pragma unroll
    for (int i = 0; i < 2; ++i) {
        const int rA = wid * 32 + i * 16 + lrow;             // 0..127
        gA[i] = (const __bf16*)xb + (size_t)(m0 + rA) * KP2 + cch * 8;
        // B staging rows wid*32..+31 lie entirely in gate g = wid
        gB[i] = (const __bf16*)wxt +
                (size_t)(wid * HDIM + n0 + i * 16 + lrow) * KP2 + cch * 8;
        lofs[i] = (wid * 32 + i * 16) * 32;                  // wave-uniform
    }

    auto stage = [&](int tile, int p) {
        const int ko = tile * 32;
        const int po = p * BUFE;
#pragma unroll
        for (int i = 0; i < 2; ++i) {
            __builtin_amdgcn_global_load_lds(
                (const __attribute__((address_space(1))) void*)(gA[i] + ko),
                (__attribute__((address_space(3))) void*)(smA + po + lofs[i]),
                16, 0, 0);
            __builtin_amdgcn_global_load_lds(
                (const __attribute__((address_space(1))) void*)(gB[i] + ko),
                (__attribute__((address_space(3))) void*)(smB + po + lofs[i]),
                16, 0, 0);
        }
    };

    const int slr = (fhi ^ ((fl15 >> 1) & 3)) * 8;   // de-swizzled read slot

    auto compute = [&](int p) {
        const int po = p * BUFE;
        bf16x8 af[4], bfr[4];
#pragma unroll
        for (int rt = 0; rt < 4; ++rt)
            af[rt] = *(const bf16x8*)(smA + po +
                (wm * 64 + rt * 16 + fl15) * 32 + slr);
#pragma unroll
        for (int g = 0; g < 4; ++g)
            bfr[g] = *(const bf16x8*)(smB + po +
                (g * 32 + wn * 16 + fl15) * 32 + slr);
#pragma unroll
        for (int g = 0; g < 4; ++g)
#pragma unroll
            for (int rt = 0; rt < 4; ++rt)
                acc[g][rt] = __builtin_amdgcn_mfma_f32_16x16x32_bf16(
                    af[rt], bfr[g], acc[g][rt], 0, 0, 0);
    };

    // ---- single-barrier counted pipeline (see header comment) ----
    stage(0, 0);
#pragma unroll
    for (int kt = 0; kt < NKT32; ++kt) {
        asm volatile("s_waitcnt vmcnt(0)" ::: "memory");
        asm volatile("s_barrier" ::: "memory");
        if (kt + 1 < NKT32) stage(kt + 1, (kt + 1) & 1);
        compute(kt & 1);
    }

    // Epilogue. C/D layout: col=lane&15, row=(lane>>4)*4+reg (m89/m91).
    const int colg = n0 + wn * 16 + fl15;        // h-unit index
    float zsum[4], wxr[4];
#pragma unroll
    for (int g = 0; g < 4; ++g) {
        float z = bh[g * HDIM + colg];
#pragma unroll
        for (int j = 0; j < 16; ++j)
            z += zh_w[j * ZDIM + g * HDIM + colg];
        zsum[g] = z;
        // rank-1 r column: Wx row 576 (f32, read direct from pristine input)
        wxr[g] = wx[(size_t)576 * ZDIM + g * HDIM + colg];
    }
    const float cv = cvec[colg];
#pragma unroll
    for (int rt = 0; rt < 4; ++rt) {
#pragma unroll
        for (int r = 0; r < 4; ++r) {
            const int row = m0 + wm * 64 + rt * 16 + (fhi << 2) + r;
            const float rv = r_prev[row];
            const float zi = acc[0][rt][r] + zsum[0] + rv * wxr[0];
            const float zf = acc[1][rt][r] + zsum[1] + rv * wxr[1];
            const float zg = acc[2][rt][r] + zsum[2] + rv * wxr[2];
            const float zo = acc[3][rt][r] + zsum[3] + rv * wxr[3];
            const float cn = sigmoid_f(zf) * cv + sigmoid_f(zi) * tanh_f(zg);
            const float hn = sigmoid_f(zo) * tanh_f(cn);
            hout[(size_t)row * HDIM + colg] = __float2bfloat16(hn);
        }
    }
}

// ---------------------------------------------------------------------------
// Policy+value head v3 (unchanged — proven). Block = 16 rows, 512 threads.
// ---------------------------------------------------------------------------
__global__ __launch_bounds__(512) void head_kernel(
    const __hip_bfloat16* __restrict__ hnew,  // [4096][2048] bf16
    const __hip_bfloat16* __restrict__ waT,   // [64][2048] bf16
    const float* __restrict__ wv,             // [2048] f32
    const float* __restrict__ ba, const float* __restrict__ bv,
    float* __restrict__ probs, float* __restrict__ vout)
{
    __shared__ float lg[8][16][68];    // 34.8KB partial logits
    __shared__ float vpart[8][16];
    const int t    = threadIdx.x;
    const int lane = t & 63;
    const int w    = t >> 6;           // k-eighth 0..7
    const int r0   = blockIdx.x * 16;
    const int fl15 = lane & 15, fhi = lane >> 4;
    const int k0   = w * 256;

    const __bf16* arow = (const __bf16*)hnew +
        (size_t)(r0 + fl15) * HDIM + k0 + fhi * 8;
    const __bf16* brow = (const __bf16*)waT +
        (size_t)fl15 * HDIM + k0 + fhi * 8;
    const float* wvp = wv + k0 + fhi * 8;

    accx4 acc[4] = {};
    float va0 = 0.f, va1 = 0.f;
#pragma unroll
    for (int kk = 0; kk < 256; kk += 32) {
        bf16x8 af = *(const bf16x8*)(arow + kk);
#pragma unroll
        for (int a = 0; a < 4; ++a) {
            bf16x8 bf = *(const bf16x8*)(brow + (size_t)a * 16 * HDIM + kk);
            acc[a] = __builtin_amdgcn_mfma_f32_16x16x32_bf16(
                af, bf, acc[a], 0, 0, 0);
        }
#pragma unroll
        for (int j = 0; j < 4; ++j) {
            va0 = fmaf((float)af[j],     wvp[kk + j],     va0);
            va1 = fmaf((float)af[j + 4], wvp[kk + j + 4], va1);
        }
    }
#pragma unroll
    for (int a = 0; a < 4; ++a)
#pragma unroll
        for (int r = 0; r < 4; ++r)
            lg[w][fhi * 4 + r][a * 16 + fl15] = acc[a][r];
    float va = va0 + va1;
    va += __shfl_xor(va, 16);
    va += __shfl_xor(va, 32);
    if (lane < 16) vpart[w][lane] = va;
    __syncthreads();

    const float bav = ba[lane];
#pragma unroll
    for (int i = 0; i < 2; ++i) {
        const int row = w * 2 + i;
        float logit = bav;
#pragma unroll
        for (int p = 0; p < 8; ++p)
            logit += lg[p][row][lane];
        float m = logit;
#pragma unroll
        for (int mask = 32; mask >= 1; mask >>= 1)
            m = fmaxf(m, __shfl_xor(m, mask));
        const float e = __expf(logit - m);
        float ssum = e;
#pragma unroll
        for (int mask = 32; mask >= 1; mask >>= 1)
            ssum += __shfl_xor(ssum, mask);
        probs[(size_t)(r0 + row) * 64 + lane] = e / ssum;
    }
    if (t < 16) {
        float v = bv[0];
#pragma unroll
        for (int p = 0; p < 8; ++p)
            v += vpart[p][t];
        vout[r0 + t] = v;
    }
}

// ---------------------------------------------------------------------------
extern "C" void kernel_launch(void* const* d_in, const int* in_sizes, int n_in,
                              void* d_out, int out_size, void* d_ws,
                              size_t ws_size, hipStream_t stream)
{
    const float* s      = (const float*)d_in[0];
    const float* a_prev = (const float*)d_in[1];
    const float* r_prev = (const float*)d_in[2];
    const float* h      = (const float*)d_in[3];
    const float* c      = (const float*)d_in[4];
    const float* Wx     = (const float*)d_in[5];
    const float* Wh     = (const float*)d_in[6];
    const float* bh     = (const float*)d_in[7];
    const float* Wa     = (const float*)d_in[8];
    const float* ba     = (const float*)d_in[9];
    const float* Wv     = (const float*)d_in[10];
    const float* bv     = (const float*)d_in[11];

    float* out   = (float*)d_out;
    float* probs = out;                        // [4096*64]
    float* vout  = out + (size_t)BATCH * ADIM; // [4096]

    // Workspace layout (16B-aligned)
    char* ws = (char*)d_ws;
    __hip_bfloat16* xb   = (__hip_bfloat16*)ws;                 //  4,718,592
    __hip_bfloat16* wxt  = (__hip_bfloat16*)(ws + 4718592);     //  9,437,184
    __hip_bfloat16* waT  = (__hip_bfloat16*)(ws + 14155776);    //    262,144
    float* zh_w          = (float*)(ws + 14417920);             //    524,288
    __hip_bfloat16* hnew = (__hip_bfloat16*)(ws + 14942208);    // 16,777,216
    // total 31,719,424 bytes

    setup_kernel<<<5888, 256, 0, stream>>>(
        s, a_prev, h, Wx, Wh, Wa, xb, wxt, waT, zh_w);
    lstm_gemm<<<dim3(BATCH / 128, HDIM / 32), 256, 0, stream>>>(
        xb, wxt, zh_w, bh, c, Wx, r_prev, hnew);
    head_kernel<<<BATCH / 16, 512, 0, stream>>>(
        hnew, waT, Wv, ba, bv, probs, vout);
}

// Round 3
// 227.546 us; speedup vs baseline: 1.0026x; 1.0026x over previous
//
#include <hip/hip_runtime.h>
#include <hip/hip_bf16.h>

// Problem constants
#define BATCH   4096
#define SDIM    512
#define ADIM    64
#define IDIM    577           // 512 + 64 + 1
#define KP2     576           // GEMM K = s+a exactly; r handled rank-1
#define NKT64   9             // K-tiles of 64
#define HDIM    2048
#define ZDIM    8192          // 4*HDIM
#define BUFB    (128 * 64)    // LDS elems per B buffer (16KB)

typedef __attribute__((ext_vector_type(8))) __bf16 bf16x8;
typedef __attribute__((ext_vector_type(4))) float  accx4;

// ---------------------------------------------------------------------------
// Fused setup kernel. Role by flat blockIdx:
//   [0,1152)     transpose Wx rows 0..575: 64k x 64n tiles -> wxt [8192][576]
//   [1152,1664)  zh partials (16 k-splits): zh_w[ky][n] = sum h*Wh
//   [1664,5760)  prep xb rows -> MFMA-FRAGMENT layout (R13 change):
//                xbf block (t16 = row/16, kc32 = k/32) of 512 bf16; lane
//                l = ((k32>>3)<<4)|(row&15) holds elems j = k32&7. The GEMM
//                loads A frags with ONE coalesced dwordx4 (lane*16B).
//   [5760,5888)  transpose Wa [2048,64]f32 -> waT [64][2048]bf16
// ---------------------------------------------------------------------------
__global__ __launch_bounds__(256) void setup_kernel(
    const float* __restrict__ s, const float* __restrict__ a_prev,
    const float* __restrict__ h,
    const float* __restrict__ wx, const float* __restrict__ wh,
    const float* __restrict__ wa,
    __hip_bfloat16* __restrict__ xb, __hip_bfloat16* __restrict__ wxt,
    __hip_bfloat16* __restrict__ waT, float* __restrict__ zh_w)
{
    __shared__ float stile[64 * 65];        // 16.6KB, stride 65 (conflict-free)
    const int bid = blockIdx.x;
    const int t = threadIdx.x;

    if (bid < 1152) {                       // ---- transpose Wx (64k x 64n)
        const int kt2 = bid >> 7;           // 0..8
        const int nt  = bid & 127;          // 0..127
        const int c4  = t & 15;             // float4 column
        const int rr  = t >> 4;             // 0..15
#pragma unroll
        for (int i = 0; i < 4; ++i) {
            const int r = rr + i * 16;      // k within tile
            const int k = kt2 * 64 + r;
            float4 v =
                *(const float4*)(wx + (size_t)k * ZDIM + nt * 64 + c4 * 4);
            *(float4*)(stile + r * 65 + c4 * 4) = v;
        }
        __syncthreads();
        const int ch = t & 7;               // k-chunk
#pragma unroll
        for (int i = 0; i < 2; ++i) {
            const int nr = (t >> 3) + i * 32;   // n-row 0..63
            bf16x8 w8;
#pragma unroll
            for (int j = 0; j < 8; ++j)
                w8[j] = (__bf16)stile[(ch * 8 + j) * 65 + nr];
            *(bf16x8*)(wxt + (size_t)(nt * 64 + nr) * KP2 + kt2 * 64 + ch * 8)
                = w8;
        }
    } else if (bid < 1664) {                // ---- zh partials (16 k-splits)
        const int zb = bid - 1152;
        const int nb = zb & 31, ky = zb >> 5;       // nb 0..31, ky 0..15
        const int n  = nb * 256 + t;
        const float* hp  = h + ky * 128;
        const float* whp = wh + (size_t)ky * 128 * ZDIM + n;
        float p = 0.0f;
#pragma unroll 32
        for (int kk = 0; kk < 128; ++kk)
            p = fmaf(hp[kk], whp[(size_t)kk * ZDIM], p);
        zh_w[ky * ZDIM + n] = p;
    } else if (bid < 5760) {                // ---- prep xbf fragment blocks
        const int row = bid - 1664;
        if (t < 72) {                       // chunk ch of 8 cols; 0..63=s 64..71=a
            const int ch  = t;
            const int t16 = row >> 4, fl = row & 15;
            float4 v0, v1;
            if (ch < 64) {
                v0 = *(const float4*)(s + (size_t)row * SDIM + ch * 8);
                v1 = *(const float4*)(s + (size_t)row * SDIM + ch * 8 + 4);
            } else {
                v0 = *(const float4*)(a_prev + (size_t)row * ADIM + (ch - 64) * 8);
                v1 = *(const float4*)(a_prev + (size_t)row * ADIM + (ch - 64) * 8 + 4);
            }
            bf16x8 w;
            w[0] = (__bf16)v0.x; w[1] = (__bf16)v0.y;
            w[2] = (__bf16)v0.z; w[3] = (__bf16)v0.w;
            w[4] = (__bf16)v1.x; w[5] = (__bf16)v1.y;
            w[6] = (__bf16)v1.z; w[7] = (__bf16)v1.w;
            const int kc32 = ch >> 2, sub = ch & 3;   // lane = sub*16 + fl
            *(bf16x8*)((__bf16*)xb +
                ((size_t)(t16 * 18 + kc32) * 64 + sub * 16 + fl) * 8) = w;
        }
    } else {                                // ---- transpose Wa (32k x 32a)
        const int wb = bid - 5760;
        const int kt = wb >> 1, at = wb & 1;
        const int c  = t & 31, r0 = t >> 5;
#pragma unroll
        for (int i = 0; i < 4; ++i) {
            int r = r0 + i * 8;             // k within tile
            stile[r * 33 + c] = wa[(size_t)(kt * 32 + r) * ADIM + at * 32 + c];
        }
        __syncthreads();
#pragma unroll
        for (int i = 0; i < 4; ++i) {
            int r = r0 + i * 8;             // action within tile
            waT[(size_t)(at * 32 + r) * HDIM + kt * 32 + c] =
                __float2bfloat16(stile[c * 33 + r]);
        }
    }
}

// ---------------------------------------------------------------------------
// Main bf16 MFMA GEMM + fused LSTM epilogue.
// R13: A in REGISTERS (direct from fragment-ordered xbf, L2-resident 4.7MB),
// B-only LDS with 3 buffers (48KB -> 3 blocks/CU, 12 waves) and depth-2
// prefetch. Per-iter per-wave VMEM: 8 A dwordx4 (to regs) + 4 B
// global_load_lds. Single barrier per tile; issues AFTER the barrier.
// Wait math (steady kt): outstanding = [B(kt) (iter kt-2), A(kt), B(kt+1)
// (iter kt-1)] = 16 -> vmcnt(4) completes B(kt)+A(kt), leaves B(kt+1) in
// flight. Every waited load had >= 1 full compute phase + barrier to land.
// Race audit: B(kt+2) writes smB[(kt+2)%3], last read by compute(kt-1);
// all waves' compute(kt-1) ds_reads complete before they pass barrier(kt)
// (data consumed by MFMAs preceding the barrier), and the issue is after
// barrier(kt) in program order (asm memory clobbers pin ordering). A-reg
// correctness is additionally covered by compiler dependence-tracked waits.
// ---------------------------------------------------------------------------
__device__ __forceinline__ float rcp_f(float x) {
    return __builtin_amdgcn_rcpf(x);
}
__device__ __forceinline__ float sigmoid_f(float x) {
    return rcp_f(1.0f + __expf(-x));          // stable: x->-inf => rcp(inf)=0
}
__device__ __forceinline__ float tanh_f(float x) {
    return 1.0f - 2.0f * rcp_f(1.0f + __expf(2.0f * x)); // stable both ends
}

__global__ __launch_bounds__(256, 3) void lstm_gemm(
    const __hip_bfloat16* __restrict__ xbf,  // [256][18][512] bf16 frag blocks
    const __hip_bfloat16* __restrict__ wxt,  // [8192][576] bf16 (n-major)
    const float* __restrict__ zh_w,          // [16][8192] k-split partials
    const float* __restrict__ bh,            // [8192]
    const float* __restrict__ cvec,          // [2048]
    const float* __restrict__ wx,            // [577][8192] f32 (row 576 used)
    const float* __restrict__ r_prev,        // [4096]
    __hip_bfloat16* __restrict__ hout)       // [4096][2048] bf16
{
    __shared__ __bf16 smB[3 * BUFB];   // 48KB  [buf][zcol][slot swizzled]
    const int t    = threadIdx.x;
    const int lane = t & 63;
    const int wid  = t >> 6;
    const int m0   = blockIdx.x * 128;
    const int m16  = blockIdx.x * 8;   // m0/16
    const int n0   = blockIdx.y * 32;
    const int wm   = wid >> 1, wn = wid & 1;
    const int fl15 = lane & 15;
    const int fhi  = lane >> 4;        // 0..3

    accx4 acc[4][4] = {};              // [gate][rowtile]

    // ---- B staging addresses (loop-invariant, R1-proven pattern) ----
    const int srow = lane >> 3;        // 0..7
    const int slot = lane & 7;
    const int cch  = slot ^ srow;      // swizzled source chunk (involution)
    const __bf16* gB[4]; int lofs[4];
#pragma unroll
    for (int i = 0; i < 4; ++i) {
        const int r = wid * 32 + i * 8 + srow;               // 0..127
        const int g = r >> 5, nn = r & 31;
        gB[i] = (const __bf16*)wxt +
                (size_t)(g * HDIM + n0 + nn) * KP2 + cch * 8;
        lofs[i] = (wid * 32 + i * 8) * 64;                   // wave-uniform
    }

    auto stageB = [&](int tile, int buf) {
        const int ko = tile * 64;
        const int po = buf * BUFB;
#pragma unroll
        for (int i = 0; i < 4; ++i)
            __builtin_amdgcn_global_load_lds(
                (const __attribute__((address_space(1))) void*)(gB[i] + ko),
                (__attribute__((address_space(3))) void*)(smB + po + lofs[i]),
                16, 0, 0);
    };

    // ---- A fragment loads: one coalesced dwordx4 per frag ----
    const __bf16* abase = (const __bf16*)xbf + lane * 8;
    auto loadA = [&](int tile, bf16x8 (&dst)[8]) {
#pragma unroll
        for (int rt = 0; rt < 4; ++rt)
#pragma unroll
            for (int hf = 0; hf < 2; ++hf)
                dst[rt * 2 + hf] = *(const bf16x8*)(abase +
                    (size_t)((m16 + wm * 4 + rt) * 18 + tile * 2 + hf) * 512);
    };

    auto compute = [&](int buf, const bf16x8 (&aR)[8]) {
        const int po = buf * BUFB;
#pragma unroll
        for (int hf = 0; hf < 2; ++hf) {
            const int ck = hf * 4 + fhi;                     // wanted chunk
            const int sl = (ck ^ (fl15 & 7)) * 8;            // de-swizzle
            bf16x8 bfr[4];
#pragma unroll
            for (int g = 0; g < 4; ++g)
                bfr[g] = *(const bf16x8*)(smB + po +
                    (g * 32 + wn * 16 + fl15) * 64 + sl);
#pragma unroll
            for (int g = 0; g < 4; ++g)
#pragma unroll
                for (int rt = 0; rt < 4; ++rt)
                    acc[g][rt] = __builtin_amdgcn_mfma_f32_16x16x32_bf16(
                        aR[rt * 2 + hf], bfr[g], acc[g][rt], 0, 0, 0);
        }
    };

    bf16x8 aA[8], aB[8];

    // ---- prologue: B(0), A(0), B(1) in flight ----
    stageB(0, 0);
    loadA(0, aA);
    stageB(1, 1);
#pragma unroll
    for (int kt = 0; kt < NKT64; ++kt) {
        if (kt < NKT64 - 1)
            asm volatile("s_waitcnt vmcnt(4)" ::: "memory");
        else
            asm volatile("s_waitcnt vmcnt(0)" ::: "memory");
        asm volatile("s_barrier" ::: "memory");
        if (kt + 1 < NKT64) {
            if (kt & 1) loadA(kt + 1, aA); else loadA(kt + 1, aB);
        }
        if (kt + 2 < NKT64) stageB(kt + 2, (kt + 2) % 3);
        if (kt & 1) compute(kt % 3, aB); else compute(kt % 3, aA);
    }

    // Epilogue. C/D layout: col=lane&15, row=(lane>>4)*4+reg (m89/m91).
    const int colg = n0 + wn * 16 + fl15;        // h-unit index
    float zsum[4], wxr[4];
#pragma unroll
    for (int g = 0; g < 4; ++g) {
        float z = bh[g * HDIM + colg];
#pragma unroll
        for (int j = 0; j < 16; ++j)
            z += zh_w[j * ZDIM + g * HDIM + colg];
        zsum[g] = z;
        // rank-1 r column: Wx row 576 (f32, read direct from pristine input)
        wxr[g] = wx[(size_t)576 * ZDIM + g * HDIM + colg];
    }
    const float cv = cvec[colg];
#pragma unroll
    for (int rt = 0; rt < 4; ++rt) {
#pragma unroll
        for (int r = 0; r < 4; ++r) {
            const int row = m0 + wm * 64 + rt * 16 + (fhi << 2) + r;
            const float rv = r_prev[row];
            const float zi = acc[0][rt][r] + zsum[0] + rv * wxr[0];
            const float zf = acc[1][rt][r] + zsum[1] + rv * wxr[1];
            const float zg = acc[2][rt][r] + zsum[2] + rv * wxr[2];
            const float zo = acc[3][rt][r] + zsum[3] + rv * wxr[3];
            const float cn = sigmoid_f(zf) * cv + sigmoid_f(zi) * tanh_f(zg);
            const float hn = sigmoid_f(zo) * tanh_f(cn);
            hout[(size_t)row * HDIM + colg] = __float2bfloat16(hn);
        }
    }
}

// ---------------------------------------------------------------------------
// Policy+value head v3 (unchanged — proven). Block = 16 rows, 512 threads.
// ---------------------------------------------------------------------------
__global__ __launch_bounds__(512) void head_kernel(
    const __hip_bfloat16* __restrict__ hnew,  // [4096][2048] bf16
    const __hip_bfloat16* __restrict__ waT,   // [64][2048] bf16
    const float* __restrict__ wv,             // [2048] f32
    const float* __restrict__ ba, const float* __restrict__ bv,
    float* __restrict__ probs, float* __restrict__ vout)
{
    __shared__ float lg[8][16][68];    // 34.8KB partial logits
    __shared__ float vpart[8][16];
    const int t    = threadIdx.x;
    const int lane = t & 63;
    const int w    = t >> 6;           // k-eighth 0..7
    const int r0   = blockIdx.x * 16;
    const int fl15 = lane & 15, fhi = lane >> 4;
    const int k0   = w * 256;

    const __bf16* arow = (const __bf16*)hnew +
        (size_t)(r0 + fl15) * HDIM + k0 + fhi * 8;
    const __bf16* brow = (const __bf16*)waT +
        (size_t)fl15 * HDIM + k0 + fhi * 8;
    const float* wvp = wv + k0 + fhi * 8;

    accx4 acc[4] = {};
    float va0 = 0.f, va1 = 0.f;
#pragma unroll
    for (int kk = 0; kk < 256; kk += 32) {
        bf16x8 af = *(const bf16x8*)(arow + kk);
#pragma unroll
        for (int a = 0; a < 4; ++a) {
            bf16x8 bf = *(const bf16x8*)(brow + (size_t)a * 16 * HDIM + kk);
            acc[a] = __builtin_amdgcn_mfma_f32_16x16x32_bf16(
                af, bf, acc[a], 0, 0, 0);
        }
#pragma unroll
        for (int j = 0; j < 4; ++j) {
            va0 = fmaf((float)af[j],     wvp[kk + j],     va0);
            va1 = fmaf((float)af[j + 4], wvp[kk + j + 4], va1);
        }
    }
#pragma unroll
    for (int a = 0; a < 4; ++a)
#pragma unroll
        for (int r = 0; r < 4; ++r)
            lg[w][fhi * 4 + r][a * 16 + fl15] = acc[a][r];
    float va = va0 + va1;
    va += __shfl_xor(va, 16);
    va += __shfl_xor(va, 32);
    if (lane < 16) vpart[w][lane] = va;
    __syncthreads();

    const float bav = ba[lane];
#pragma unroll
    for (int i = 0; i < 2; ++i) {
        const int row = w * 2 + i;
        float logit = bav;
#pragma unroll
        for (int p = 0; p < 8; ++p)
            logit += lg[p][row][lane];
        float m = logit;
#pragma unroll
        for (int mask = 32; mask >= 1; mask >>= 1)
            m = fmaxf(m, __shfl_xor(m, mask));
        const float e = __expf(logit - m);
        float ssum = e;
#pragma unroll
        for (int mask = 32; mask >= 1; mask >>= 1)
            ssum += __shfl_xor(ssum, mask);
        probs[(size_t)(r0 + row) * 64 + lane] = e / ssum;
    }
    if (t < 16) {
        float v = bv[0];
#pragma unroll
        for (int p = 0; p < 8; ++p)
            v += vpart[p][t];
        vout[r0 + t] = v;
    }
}

// ---------------------------------------------------------------------------
extern "C" void kernel_launch(void* const* d_in, const int* in_sizes, int n_in,
                              void* d_out, int out_size, void* d_ws,
                              size_t ws_size, hipStream_t stream)
{
    const float* s      = (const float*)d_in[0];
    const float* a_prev = (const float*)d_in[1];
    const float* r_prev = (const float*)d_in[2];
    const float* h      = (const float*)d_in[3];
    const float* c      = (const float*)d_in[4];
    const float* Wx     = (const float*)d_in[5];
    const float* Wh     = (const float*)d_in[6];
    const float* bh     = (const float*)d_in[7];
    const float* Wa     = (const float*)d_in[8];
    const float* ba     = (const float*)d_in[9];
    const float* Wv     = (const float*)d_in[10];
    const float* bv     = (const float*)d_in[11];

    float* out   = (float*)d_out;
    float* probs = out;                        // [4096*64]
    float* vout  = out + (size_t)BATCH * ADIM; // [4096]

    // Workspace layout (16B-aligned)
    char* ws = (char*)d_ws;
    __hip_bfloat16* xb   = (__hip_bfloat16*)ws;                 //  4,718,592
    __hip_bfloat16* wxt  = (__hip_bfloat16*)(ws + 4718592);     //  9,437,184
    __hip_bfloat16* waT  = (__hip_bfloat16*)(ws + 14155776);    //    262,144
    float* zh_w          = (float*)(ws + 14417920);             //    524,288
    __hip_bfloat16* hnew = (__hip_bfloat16*)(ws + 14942208);    // 16,777,216
    // total 31,719,424 bytes

    setup_kernel<<<5888, 256, 0, stream>>>(
        s, a_prev, h, Wx, Wh, Wa, xb, wxt, waT, zh_w);
    lstm_gemm<<<dim3(BATCH / 128, HDIM / 32), 256, 0, stream>>>(
        xb, wxt, zh_w, bh, c, Wx, r_prev, hnew);
    head_kernel<<<BATCH / 16, 512, 0, stream>>>(
        hnew, waT, Wv, ba, bv, probs, vout);
}

// Round 4
// 198.352 us; speedup vs baseline: 1.1502x; 1.1472x over previous
//
#include <hip/hip_runtime.h>
#include <hip/hip_bf16.h>

// Problem constants
#define BATCH   4096
#define SDIM    512
#define ADIM    64
#define IDIM    577           // 512 + 64 + 1
#define KP2     576           // GEMM K = s+a exactly (9*64); r handled rank-1
#define NKT64   9             // K-tiles of 64
#define HDIM    2048
#define ZDIM    8192          // 4*HDIM
#define BUFE    (128 * 64)    // LDS elems per buffer (16KB)

typedef __attribute__((ext_vector_type(8))) __bf16 bf16x8;
typedef __attribute__((ext_vector_type(4))) __bf16 bf16x4;
typedef __attribute__((ext_vector_type(4))) float  accx4;

// ---------------------------------------------------------------------------
// Fused setup kernel (R14: zh 2x TLP via k-halving + LDS reduce; xb prep
// vectorized float4->bf16x4, 16 rows/block). Role by flat blockIdx:
//   [0,1152)     transpose Wx rows 0..575: 64k x 64n tiles -> wxt [8192][576]
//   [1152,2176)  zh partials: 1024 blocks = 16 ky x 64 nb. Block covers 128
//                n-cols; t>>7 selects k-half (64 deep); LDS pair-reduce ->
//                zh_w[ky][n] (SAME [16][8192] format as R1 gemm expects).
//   [2176,2432)  prep xb rows: 256 blocks x 16 rows, float4 loads, bf16x4
//                stores (was: 4096 blocks, scalar loads/stores)
//   [2432,2560)  transpose Wa [2048,64]f32 -> waT [64][2048]bf16
// ---------------------------------------------------------------------------
__global__ __launch_bounds__(256) void setup_kernel(
    const float* __restrict__ s, const float* __restrict__ a_prev,
    const float* __restrict__ h,
    const float* __restrict__ wx, const float* __restrict__ wh,
    const float* __restrict__ wa,
    __hip_bfloat16* __restrict__ xb, __hip_bfloat16* __restrict__ wxt,
    __hip_bfloat16* __restrict__ waT, float* __restrict__ zh_w)
{
    __shared__ float stile[64 * 65];        // 16.6KB, stride 65 (conflict-free)
    const int bid = blockIdx.x;
    const int t = threadIdx.x;

    if (bid < 1152) {                       // ---- transpose Wx (64k x 64n)
        const int kt2 = bid >> 7;           // 0..8
        const int nt  = bid & 127;          // 0..127
        const int c4  = t & 15;             // float4 column
        const int rr  = t >> 4;             // 0..15
#pragma unroll
        for (int i = 0; i < 4; ++i) {
            const int r = rr + i * 16;      // k within tile (k < 576 < 577)
            const int k = kt2 * 64 + r;
            float4 v =
                *(const float4*)(wx + (size_t)k * ZDIM + nt * 64 + c4 * 4);
            *(float4*)(stile + r * 65 + c4 * 4) = v;
        }
        __syncthreads();
        const int ch = t & 7;               // k-chunk
#pragma unroll
        for (int i = 0; i < 2; ++i) {
            const int nr = (t >> 3) + i * 32;   // n-row 0..63
            bf16x8 w8;
#pragma unroll
            for (int j = 0; j < 8; ++j)
                w8[j] = (__bf16)stile[(ch * 8 + j) * 65 + nr];
            *(bf16x8*)(wxt + (size_t)(nt * 64 + nr) * KP2 + kt2 * 64 + ch * 8)
                = w8;
        }
    } else if (bid < 2176) {                // ---- zh partials (16 ky x 64 nb)
        const int zb = bid - 1152;
        const int nb = zb & 63, ky = zb >> 6;       // nb 0..63, ky 0..15
        const int n  = nb * 128 + (t & 127);
        const int kh = t >> 7;                      // k-half 0/1
        const float* hp  = h + ky * 128 + kh * 64;
        const float* whp = wh + (size_t)(ky * 128 + kh * 64) * ZDIM + n;
        float p = 0.0f;
#pragma unroll 32
        for (int kk = 0; kk < 64; ++kk)
            p = fmaf(hp[kk], whp[(size_t)kk * ZDIM], p);
        stile[t] = p;
        __syncthreads();
        if (t < 128)
            zh_w[ky * ZDIM + n] = stile[t] + stile[t + 128];
    } else if (bid < 2432) {                // ---- prep xb (16 rows, vector)
        const int row0 = (bid - 2176) * 16;
        const int tr = t >> 4, tc = t & 15;
        const int row = row0 + tr;
        const float* srow = s + (size_t)row * SDIM;
        const float* arow = a_prev + (size_t)row * ADIM;
        __hip_bfloat16* xrow = xb + (size_t)row * KP2;
#pragma unroll
        for (int j = 0; j < 9; ++j) {
            const int c4  = j * 16 + tc;    // 0..143
            const int col = c4 * 4;
            float4 v = (col < SDIM)
                ? *(const float4*)(srow + col)
                : *(const float4*)(arow + (col - SDIM));
            bf16x4 w;
            w[0] = (__bf16)v.x; w[1] = (__bf16)v.y;
            w[2] = (__bf16)v.z; w[3] = (__bf16)v.w;
            *(bf16x4*)(xrow + col) = w;
        }
    } else {                                // ---- transpose Wa (32k x 32a)
        const int wb = bid - 2432;
        const int kt = wb >> 1, at = wb & 1;
        const int c  = t & 31, r0 = t >> 5;
#pragma unroll
        for (int i = 0; i < 4; ++i) {
            int r = r0 + i * 8;             // k within tile
            stile[r * 33 + c] = wa[(size_t)(kt * 32 + r) * ADIM + at * 32 + c];
        }
        __syncthreads();
#pragma unroll
        for (int i = 0; i < 4; ++i) {
            int r = r0 + i * 8;             // action within tile
            waT[(size_t)(at * 32 + r) * HDIM + kt * 32 + c] =
                __float2bfloat16(stile[c * 33 + r]);
        }
    }
}

// ---------------------------------------------------------------------------
// Main bf16 MFMA GEMM + fused LSTM epilogue — REVERTED VERBATIM to the
// R1-proven 55.6us form (T4 counted vmcnt, A+B LDS double-buffer, BK=64):
//   stage(kt+1); s_waitcnt vmcnt(8); s_barrier; compute(kt); s_barrier;
// The 8 prefetch loads stay in flight across both barriers and land under
// compute(kt). Race audit: buf written by stage(kt+1) was last read by
// compute(kt-1), separated by the post-compute barrier of iter kt-1.
// (R3's A-in-reg variant spilled fragments to scratch: WRITE_SIZE 16->88MB,
// VGPR budget 168 < needed ~190 — reverted.)
// ---------------------------------------------------------------------------
__device__ __forceinline__ float rcp_f(float x) {
    return __builtin_amdgcn_rcpf(x);
}
__device__ __forceinline__ float sigmoid_f(float x) {
    return rcp_f(1.0f + __expf(-x));          // stable: x->-inf => rcp(inf)=0
}
__device__ __forceinline__ float tanh_f(float x) {
    return 1.0f - 2.0f * rcp_f(1.0f + __expf(2.0f * x)); // stable both ends
}

__global__ __launch_bounds__(256, 2) void lstm_gemm(
    const __hip_bfloat16* __restrict__ xb,   // [4096][576] bf16
    const __hip_bfloat16* __restrict__ wxt,  // [8192][576] bf16 (n-major)
    const float* __restrict__ zh_w,          // [16][8192] k-split partials
    const float* __restrict__ bh,            // [8192]
    const float* __restrict__ cvec,          // [2048]
    const float* __restrict__ wx,            // [577][8192] f32 (row 576 used)
    const float* __restrict__ r_prev,        // [4096]
    __hip_bfloat16* __restrict__ hout)       // [4096][2048] bf16
{
    __shared__ __bf16 smA[2 * BUFE];   // 32KB  [buf][row][k-chunk swizzled]
    __shared__ __bf16 smB[2 * BUFE];   // 32KB  [buf][zcol][k-chunk swizzled]
    const int t    = threadIdx.x;
    const int lane = t & 63;
    const int wid  = t >> 6;
    const int m0   = blockIdx.x * 128;
    const int n0   = blockIdx.y * 32;
    const int wm   = wid >> 1, wn = wid & 1;
    const int fl15 = lane & 15;
    const int fhi  = lane >> 4;        // 0..3

    accx4 acc[4][4] = {};              // [gate][rowtile]

    // ---- staging addresses (loop-invariant) ----
    const int srow = lane >> 3;        // 0..7
    const int slot = lane & 7;
    const int cch  = slot ^ srow;      // swizzled source chunk (lane-const)
    const __bf16* gA[4]; const __bf16* gB[4]; int lofs[4];
#pragma unroll
    for (int i = 0; i < 4; ++i) {
        const int r = wid * 32 + i * 8 + srow;               // 0..127
        gA[i] = (const __bf16*)xb + (size_t)(m0 + r) * KP2 + cch * 8;
        const int g = r >> 5, nn = r & 31;
        gB[i] = (const __bf16*)wxt +
                (size_t)(g * HDIM + n0 + nn) * KP2 + cch * 8;
        lofs[i] = (wid * 32 + i * 8) * 64;                   // wave-uniform
    }

    auto stage = [&](int tile, int p) {
        const int ko = tile * 64;
        const int po = p * BUFE;
#pragma unroll
        for (int i = 0; i < 4; ++i) {
            __builtin_amdgcn_global_load_lds(
                (const __attribute__((address_space(1))) void*)(gA[i] + ko),
                (__attribute__((address_space(3))) void*)(smA + po + lofs[i]),
                16, 0, 0);
            __builtin_amdgcn_global_load_lds(
                (const __attribute__((address_space(1))) void*)(gB[i] + ko),
                (__attribute__((address_space(3))) void*)(smB + po + lofs[i]),
                16, 0, 0);
        }
    };

    auto compute = [&](int p) {
        const int po = p * BUFE;
#pragma unroll
        for (int hf = 0; hf < 2; ++hf) {
            const int ck = hf * 4 + fhi;                     // wanted chunk
            const int sl = (ck ^ (fl15 & 7)) * 8;            // de-swizzle
            bf16x8 af[4], bfr[4];
#pragma unroll
            for (int rt = 0; rt < 4; ++rt)
                af[rt] = *(const bf16x8*)(smA + po +
                    (wm * 64 + rt * 16 + fl15) * 64 + sl);
#pragma unroll
            for (int g = 0; g < 4; ++g)
                bfr[g] = *(const bf16x8*)(smB + po +
                    (g * 32 + wn * 16 + fl15) * 64 + sl);
#pragma unroll
            for (int g = 0; g < 4; ++g)
#pragma unroll
                for (int rt = 0; rt < 4; ++rt)
                    acc[g][rt] = __builtin_amdgcn_mfma_f32_16x16x32_bf16(
                        af[rt], bfr[g], acc[g][rt], 0, 0, 0);
        }
    };

    // ---- T4 counted-vmcnt pipeline (see header comment) ----
    stage(0, 0);
    asm volatile("s_waitcnt vmcnt(0)" ::: "memory");
    __builtin_amdgcn_s_barrier();
#pragma unroll
    for (int kt = 0; kt < NKT64 - 1; ++kt) {
        stage(kt + 1, (kt + 1) & 1);   // 8 loads in flight across barriers
        asm volatile("s_waitcnt vmcnt(8)" ::: "memory");  // tile kt landed
        __builtin_amdgcn_s_barrier();  // publish buf[kt&1]
        compute(kt & 1);
        __builtin_amdgcn_s_barrier();  // all reads of buf[kt&1] done
    }
    asm volatile("s_waitcnt vmcnt(0)" ::: "memory");      // tile 8 landed
    __builtin_amdgcn_s_barrier();
    compute((NKT64 - 1) & 1);          // last tile

    // Epilogue. C/D layout: col=lane&15, row=(lane>>4)*4+reg (m89/m91).
    const int colg = n0 + wn * 16 + fl15;        // h-unit index
    float zsum[4], wxr[4];
#pragma unroll
    for (int g = 0; g < 4; ++g) {
        float z = bh[g * HDIM + colg];
#pragma unroll
        for (int j = 0; j < 16; ++j)
            z += zh_w[j * ZDIM + g * HDIM + colg];
        zsum[g] = z;
        // rank-1 r column: Wx row 576 (f32, read direct from pristine input)
        wxr[g] = wx[(size_t)576 * ZDIM + g * HDIM + colg];
    }
    const float cv = cvec[colg];
#pragma unroll
    for (int rt = 0; rt < 4; ++rt) {
#pragma unroll
        for (int r = 0; r < 4; ++r) {
            const int row = m0 + wm * 64 + rt * 16 + (fhi << 2) + r;
            const float rv = r_prev[row];
            const float zi = acc[0][rt][r] + zsum[0] + rv * wxr[0];
            const float zf = acc[1][rt][r] + zsum[1] + rv * wxr[1];
            const float zg = acc[2][rt][r] + zsum[2] + rv * wxr[2];
            const float zo = acc[3][rt][r] + zsum[3] + rv * wxr[3];
            const float cn = sigmoid_f(zf) * cv + sigmoid_f(zi) * tanh_f(zg);
            const float hn = sigmoid_f(zo) * tanh_f(cn);
            hout[(size_t)row * HDIM + colg] = __float2bfloat16(hn);
        }
    }
}

// ---------------------------------------------------------------------------
// Policy+value head v3 (unchanged — proven). Block = 16 rows, 512 threads.
// ---------------------------------------------------------------------------
__global__ __launch_bounds__(512) void head_kernel(
    const __hip_bfloat16* __restrict__ hnew,  // [4096][2048] bf16
    const __hip_bfloat16* __restrict__ waT,   // [64][2048] bf16
    const float* __restrict__ wv,             // [2048] f32
    const float* __restrict__ ba, const float* __restrict__ bv,
    float* __restrict__ probs, float* __restrict__ vout)
{
    __shared__ float lg[8][16][68];    // 34.8KB partial logits
    __shared__ float vpart[8][16];
    const int t    = threadIdx.x;
    const int lane = t & 63;
    const int w    = t >> 6;           // k-eighth 0..7
    const int r0   = blockIdx.x * 16;
    const int fl15 = lane & 15, fhi = lane >> 4;
    const int k0   = w * 256;

    const __bf16* arow = (const __bf16*)hnew +
        (size_t)(r0 + fl15) * HDIM + k0 + fhi * 8;
    const __bf16* brow = (const __bf16*)waT +
        (size_t)fl15 * HDIM + k0 + fhi * 8;
    const float* wvp = wv + k0 + fhi * 8;

    accx4 acc[4] = {};
    float va0 = 0.f, va1 = 0.f;
#pragma unroll
    for (int kk = 0; kk < 256; kk += 32) {
        bf16x8 af = *(const bf16x8*)(arow + kk);
#pragma unroll
        for (int a = 0; a < 4; ++a) {
            bf16x8 bf = *(const bf16x8*)(brow + (size_t)a * 16 * HDIM + kk);
            acc[a] = __builtin_amdgcn_mfma_f32_16x16x32_bf16(
                af, bf, acc[a], 0, 0, 0);
        }
#pragma unroll
        for (int j = 0; j < 4; ++j) {
            va0 = fmaf((float)af[j],     wvp[kk + j],     va0);
            va1 = fmaf((float)af[j + 4], wvp[kk + j + 4], va1);
        }
    }
#pragma unroll
    for (int a = 0; a < 4; ++a)
#pragma unroll
        for (int r = 0; r < 4; ++r)
            lg[w][fhi * 4 + r][a * 16 + fl15] = acc[a][r];
    float va = va0 + va1;
    va += __shfl_xor(va, 16);
    va += __shfl_xor(va, 32);
    if (lane < 16) vpart[w][lane] = va;
    __syncthreads();

    const float bav = ba[lane];
#pragma unroll
    for (int i = 0; i < 2; ++i) {
        const int row = w * 2 + i;
        float logit = bav;
#pragma unroll
        for (int p = 0; p < 8; ++p)
            logit += lg[p][row][lane];
        float m = logit;
#pragma unroll
        for (int mask = 32; mask >= 1; mask >>= 1)
            m = fmaxf(m, __shfl_xor(m, mask));
        const float e = __expf(logit - m);
        float ssum = e;
#pragma unroll
        for (int mask = 32; mask >= 1; mask >>= 1)
            ssum += __shfl_xor(ssum, mask);
        probs[(size_t)(r0 + row) * 64 + lane] = e / ssum;
    }
    if (t < 16) {
        float v = bv[0];
#pragma unroll
        for (int p = 0; p < 8; ++p)
            v += vpart[p][t];
        vout[r0 + t] = v;
    }
}

// ---------------------------------------------------------------------------
extern "C" void kernel_launch(void* const* d_in, const int* in_sizes, int n_in,
                              void* d_out, int out_size, void* d_ws,
                              size_t ws_size, hipStream_t stream)
{
    const float* s      = (const float*)d_in[0];
    const float* a_prev = (const float*)d_in[1];
    const float* r_prev = (const float*)d_in[2];
    const float* h      = (const float*)d_in[3];
    const float* c      = (const float*)d_in[4];
    const float* Wx     = (const float*)d_in[5];
    const float* Wh     = (const float*)d_in[6];
    const float* bh     = (const float*)d_in[7];
    const float* Wa     = (const float*)d_in[8];
    const float* ba     = (const float*)d_in[9];
    const float* Wv     = (const float*)d_in[10];
    const float* bv     = (const float*)d_in[11];

    float* out   = (float*)d_out;
    float* probs = out;                        // [4096*64]
    float* vout  = out + (size_t)BATCH * ADIM; // [4096]

    // Workspace layout (16B-aligned)
    char* ws = (char*)d_ws;
    __hip_bfloat16* xb   = (__hip_bfloat16*)ws;                 //  4,718,592
    __hip_bfloat16* wxt  = (__hip_bfloat16*)(ws + 4718592);     //  9,437,184
    __hip_bfloat16* waT  = (__hip_bfloat16*)(ws + 14155776);    //    262,144
    float* zh_w          = (float*)(ws + 14417920);             //    524,288
    __hip_bfloat16* hnew = (__hip_bfloat16*)(ws + 14942208);    // 16,777,216
    // total 31,719,424 bytes

    setup_kernel<<<2560, 256, 0, stream>>>(
        s, a_prev, h, Wx, Wh, Wa, xb, wxt, waT, zh_w);
    lstm_gemm<<<dim3(BATCH / 128, HDIM / 32), 256, 0, stream>>>(
        xb, wxt, zh_w, bh, c, Wx, r_prev, hnew);
    head_kernel<<<BATCH / 16, 512, 0, stream>>>(
        hnew, waT, Wv, ba, bv, probs, vout);
}